// Round 11
// baseline (193.188 us; speedup 1.0000x reference)
//
#include <hip/hip_runtime.h>

#define HW 4096
#define NC 256
#define NP 8
#define NB 32
#define SUB 64             // hw per sub-chunk
#define CHW 128            // hw per block (2 sub-chunks)
#define NCH (HW / CHW)     // 32 chunks per batch -> grid 1024

#define FMA4(acc, v, s)                  \
  acc.x = fmaf((v).x, (s), acc.x);       \
  acc.y = fmaf((v).y, (s), acc.y);       \
  acc.z = fmaf((v).z, (s), acc.z);       \
  acc.w = fmaf((v).w, (s), acc.w)

// One 8-deep batch of phase-A FMAs: consumes xv[8] against wt rows
#define A_BATCH(xvarr, hbase)                                  \
  _Pragma("unroll")                                            \
  for (int i = 0; i < 8; ++i) {                                \
    int c = c0 + (hbase) + i * 4 + cr;                         \
    float4 wA = *(const float4*)&wt[c][0];                     \
    float4 wB = *(const float4*)&wt[c][4];                     \
    FMA4(s4[0], xvarr[i], wA.x);                               \
    FMA4(s4[1], xvarr[i], wA.y);                               \
    FMA4(s4[2], xvarr[i], wA.z);                               \
    FMA4(s4[3], xvarr[i], wA.w);                               \
    FMA4(s4[4], xvarr[i], wB.x);                               \
    FMA4(s4[5], xvarr[i], wB.y);                               \
    FMA4(s4[6], xvarr[i], wB.z);                               \
    FMA4(s4[7], xvarr[i], wB.w);                               \
  }

// ---------------- Fused: per (b, 128-hw chunk) block; grid 1024 ----------------
// R10 structure (deep 8-wide float4 batches; W^T LDS; per-lane-complete
// contractions) + chunk=128 (halves W-stage & partial traffic) + T14 split:
// sub-chunk 1's first load batch issues BEFORE phase B of sub-chunk 0, so HBM
// latency hides under B's L2-reads/FMAs. Only 32 VGPR held across B (R5: 64
// held across barriers spilled -> WRITE_SIZE tripwire).
// e = exp(score+bias); no max-subtract (|s|<~5; ratios identical; absmax
// ~1e-7 validated R1-R10).
__global__ __launch_bounds__(256) void k_fused(
    const float* __restrict__ x, const float* __restrict__ Wm,
    const float* __restrict__ bias, float* __restrict__ partial,
    float* __restrict__ psum) {
  __shared__ __align__(16) float wt[NC][NP];       // 8 KB W^T
  __shared__ __align__(16) float sp[4][NP][SUB];   // 8 KB score partials (reused per sub)
  __shared__ __align__(16) float els[2][NP][68];   // 4.4 KB double-buffered e

  const int bid = blockIdx.x;
  const int b = bid >> 5;
  const int chunk = bid & 31;
  const int t = threadIdx.x, lane = t & 63, w = t >> 6;
  const float* xb = x + (size_t)b * NC * HW + chunk * CHW;

  // ---- stage W^T (once; coalesced 256B reads) ----
#pragma unroll
  for (int p = 0; p < NP; ++p) wt[t][p] = Wm[p * NC + t];
  __syncthreads();

  const int cr = lane >> 4;   // row-in-group 0..3
  const int q = lane & 15;    // float4 hw index within sub-chunk
  const int c0 = w << 6;
  const int ep = t >> 5, eh = t & 31;
  const float bia = bias[ep];
  const float* xwp0 = xb + (size_t)(c0 + cr) * HW + q * 4;        // sub 0
  const float* xwp1 = xwp0 + SUB;                                 // sub 1
  const float* xr = xb + (size_t)t * HW;                          // phase-B row

  float acc[NP];
#pragma unroll
  for (int p = 0; p < NP; ++p) acc[p] = 0.f;
  float esum_tot = 0.f;

  // ================= sub-chunk 0: phase A =================
  float4 s4[NP];
#pragma unroll
  for (int p = 0; p < NP; ++p) s4[p] = make_float4(0.f, 0.f, 0.f, 0.f);
#pragma unroll
  for (int h = 0; h < 2; ++h) {
    float4 xv[8];
#pragma unroll
    for (int i = 0; i < 8; ++i)
      xv[i] = *(const float4*)(xwp0 + (size_t)(h * 32 + i * 4) * HW);
    A_BATCH(xv, h * 32)
  }
#pragma unroll
  for (int p = 0; p < NP; ++p) {
    float4 v = s4[p];
    v.x += __shfl_xor(v.x, 16); v.y += __shfl_xor(v.y, 16);
    v.z += __shfl_xor(v.z, 16); v.w += __shfl_xor(v.w, 16);
    v.x += __shfl_xor(v.x, 32); v.y += __shfl_xor(v.y, 32);
    v.z += __shfl_xor(v.z, 32); v.w += __shfl_xor(v.w, 32);
    if (cr == 0) *(float4*)&sp[w][p][q * 4] = v;
  }
  __syncthreads();

  // ---- e-phase 0 ----
  {
    float a0 = bia, a1 = bia;
#pragma unroll
    for (int ww = 0; ww < 4; ++ww) {
      a0 += sp[ww][ep][eh];
      a1 += sp[ww][ep][eh + 32];
    }
    float e0 = expf(a0), e1 = expf(a1);
    els[0][ep][eh] = e0;
    els[0][ep][eh + 32] = e1;
    esum_tot += e0 + e1;
  }
  __syncthreads();   // els0 visible; sp free for sub 1

  // ---- T14: issue sub-chunk 1, batch h=0 (held across phase B: 32 VGPR) ----
  float4 xp[8];
#pragma unroll
  for (int i = 0; i < 8; ++i)
    xp[i] = *(const float4*)(xwp1 + (size_t)(i * 4) * HW);

  // ---- phase B 0: thread = row c=t; x re-read L1/L2-hot ----
#pragma unroll
  for (int h = 0; h < 2; ++h) {
    float4 xv[8];
#pragma unroll
    for (int j = 0; j < 8; ++j)
      xv[j] = *(const float4*)(xr + (h * 8 + j) * 4);
#pragma unroll
    for (int j = 0; j < 8; ++j) {
      const int k = h * 8 + j;
#pragma unroll
      for (int p = 0; p < NP; ++p) {
        float4 e4 = *(const float4*)&els[0][p][k * 4];  // uniform -> broadcast
        acc[p] = fmaf(xv[j].x, e4.x, acc[p]);
        acc[p] = fmaf(xv[j].y, e4.y, acc[p]);
        acc[p] = fmaf(xv[j].z, e4.z, acc[p]);
        acc[p] = fmaf(xv[j].w, e4.w, acc[p]);
      }
    }
  }

  // ================= sub-chunk 1: phase A (h0 prefetched) =================
#pragma unroll
  for (int p = 0; p < NP; ++p) s4[p] = make_float4(0.f, 0.f, 0.f, 0.f);
  A_BATCH(xp, 0)
  {
    float4 xv[8];
#pragma unroll
    for (int i = 0; i < 8; ++i)
      xv[i] = *(const float4*)(xwp1 + (size_t)(32 + i * 4) * HW);
    A_BATCH(xv, 32)
  }
#pragma unroll
  for (int p = 0; p < NP; ++p) {
    float4 v = s4[p];
    v.x += __shfl_xor(v.x, 16); v.y += __shfl_xor(v.y, 16);
    v.z += __shfl_xor(v.z, 16); v.w += __shfl_xor(v.w, 16);
    v.x += __shfl_xor(v.x, 32); v.y += __shfl_xor(v.y, 32);
    v.z += __shfl_xor(v.z, 32); v.w += __shfl_xor(v.w, 32);
    if (cr == 0) *(float4*)&sp[w][p][q * 4] = v;
  }
  __syncthreads();

  // ---- e-phase 1 ----
  {
    float a0 = bia, a1 = bia;
#pragma unroll
    for (int ww = 0; ww < 4; ++ww) {
      a0 += sp[ww][ep][eh];
      a1 += sp[ww][ep][eh + 32];
    }
    float e0 = expf(a0), e1 = expf(a1);
    els[1][ep][eh] = e0;
    els[1][ep][eh + 32] = e1;
    esum_tot += e0 + e1;
  }
  __syncthreads();

  // ---- phase B 1 ----
#pragma unroll
  for (int h = 0; h < 2; ++h) {
    float4 xv[8];
#pragma unroll
    for (int j = 0; j < 8; ++j)
      xv[j] = *(const float4*)(xr + SUB + (h * 8 + j) * 4);
#pragma unroll
    for (int j = 0; j < 8; ++j) {
      const int k = h * 8 + j;
#pragma unroll
      for (int p = 0; p < NP; ++p) {
        float4 e4 = *(const float4*)&els[1][p][k * 4];
        acc[p] = fmaf(xv[j].x, e4.x, acc[p]);
        acc[p] = fmaf(xv[j].y, e4.y, acc[p]);
        acc[p] = fmaf(xv[j].z, e4.z, acc[p]);
        acc[p] = fmaf(xv[j].w, e4.w, acc[p]);
      }
    }
  }

  // ---- epilogue: coalesced partial write + esum reduce (once) ----
#pragma unroll
  for (int p = 0; p < NP; ++p)
    partial[((size_t)bid * NP + p) * NC + t] = acc[p];

#pragma unroll
  for (int off = 16; off; off >>= 1) esum_tot += __shfl_xor(esum_tot, off);
  if (eh == 0) psum[bid * NP + ep] = esum_tot;
}

// ---------------- Reduce: out[b,p,c] = ginv * sum_ch partial ----------------
__global__ __launch_bounds__(256) void k_reduce(
    const float* __restrict__ partial, const float* __restrict__ psum,
    float* __restrict__ out) {
  int bp = blockIdx.x;  // b*8 + p
  int b = bp >> 3, p = bp & 7;
  int t = threadIdx.x, lane = t & 63, w2 = t >> 6;

  __shared__ float gv;
  if (w2 == 0) {
    float v = (lane < NCH) ? psum[(size_t)(b * NCH + lane) * NP + p] : 0.f;
#pragma unroll
    for (int off = 16; off; off >>= 1) v += __shfl_xor(v, off);
    if (lane == 0) gv = 1.0f / (v * (float)HW);
  }
  __syncthreads();
  float ginv = gv;

  float acc = 0.f;
#pragma unroll 16
  for (int ch = 0; ch < NCH; ++ch)
    acc += partial[(((size_t)b * NCH + ch) * NP + p) * NC + t];
  out[((size_t)b * NP + p) * NC + t] = acc * ginv;
}

extern "C" void kernel_launch(void* const* d_in, const int* in_sizes, int n_in,
                              void* d_out, int out_size, void* d_ws, size_t ws_size,
                              hipStream_t stream) {
  const float* x = (const float*)d_in[0];
  const float* Wm = (const float*)d_in[1];
  const float* bias = (const float*)d_in[2];
  float* out = (float*)d_out;

  float* ws = (float*)d_ws;
  float* partial = ws;                                  // 1024*8*256 floats = 8 MiB
  float* psum = ws + (size_t)NB * NCH * NP * NC;        // 1024*8 floats

  k_fused<<<NB * NCH, 256, 0, stream>>>(x, Wm, bias, partial, psum);
  k_reduce<<<NB * NP, 256, 0, stream>>>(partial, psum, out);
}

// Round 12
// 48.224 us; speedup vs baseline: 4.0061x; 4.0061x over previous
//
#include <hip/hip_runtime.h>

#define HW 4096
#define NC 256
#define NP 8
#define NB 32
#define CHW 64
#define NCH 64   // chunks per batch -> grid 2048

#define FMA4(acc, v, s)                  \
  acc.x = fmaf((v).x, (s), acc.x);       \
  acc.y = fmaf((v).y, (s), acc.y);       \
  acc.z = fmaf((v).z, (s), acc.z);       \
  acc.w = fmaf((v).w, (s), acc.w)

// W^T during phase A; els[8][64] after (lifetimes disjoint: wt last read
// before the first barrier, els first written after it).
#define WT(c, pp) wt_els[(c) * NP + (pp)]
#define ELS(pp, hw) wt_els[(pp) * 64 + (hw)]

// One 8-deep batch of phase-A FMAs: consumes xv[8] against W^T rows
#define A_BATCH(xvarr, hbase)                                  \
  _Pragma("unroll")                                            \
  for (int i = 0; i < 8; ++i) {                                \
    int c = c0 + (hbase) + i * 4 + cr;                         \
    float4 wA = *(const float4*)&WT(c, 0);                     \
    float4 wB = *(const float4*)&WT(c, 4);                     \
    FMA4(s4[0], xvarr[i], wA.x);                               \
    FMA4(s4[1], xvarr[i], wA.y);                               \
    FMA4(s4[2], xvarr[i], wA.z);                               \
    FMA4(s4[3], xvarr[i], wA.w);                               \
    FMA4(s4[4], xvarr[i], wB.x);                               \
    FMA4(s4[5], xvarr[i], wB.y);                               \
    FMA4(s4[6], xvarr[i], wB.z);                               \
    FMA4(s4[7], xvarr[i], wB.w);                               \
  }

// ---------------- Fused: per (b, 64-hw chunk) block; grid 2048 ----------------
// R10 phase A (deep 8-wide coalesced float4 batches, W^T LDS, once-only
// shuffles) + NEW: each loaded batch is ds_written into a seg-XOR-swizzled
// LDS tile; phase B reads LDS (conflict-free) instead of re-reading global
// with 64-divergent-line loads (kills the ~1024 TA transactions/wave).
// Swizzle: row c, logical 16B-seg q stored at slot q^(c&7); phase-B row-read
// of seg k fetches slot k^(t&7) -> logical k. Both sides spread 64 lanes
// across all 8 bank-quads (baseline b128 cost); unswizzled would be 8x.
// e = exp(score+bias); no max-subtract (|s|<~5; ratios identical; absmax
// ~1e-7 validated R1-R11). LDS = 64+8+8 = 80 KB -> 2 blocks/CU.
__global__ __launch_bounds__(256) void k_fused(
    const float* __restrict__ x, const float* __restrict__ Wm,
    const float* __restrict__ bias, float* __restrict__ partial,
    float* __restrict__ psum) {
  __shared__ __align__(16) float xs[NC][64];       // 64 KB swizzled x-tile
  __shared__ __align__(16) float sp[4][NP][CHW];   // 8 KB score partials
  __shared__ __align__(16) float wt_els[NC * NP];  // 8 KB (wt, then els)

  const int bid = blockIdx.x;
  const int b = bid >> 6;
  const int chunk = bid & 63;
  const int t = threadIdx.x, lane = t & 63, w = t >> 6;
  const float* xb = x + (size_t)b * NC * HW + chunk * CHW;

  // ---- stage W^T (once; one-time minor write conflicts acceptable) ----
#pragma unroll
  for (int p = 0; p < NP; ++p) WT(t, p) = Wm[p * NC + t];
  __syncthreads();

  // ---- Phase A: scores; wave w -> c in [64w,64w+64) ----
  const int cr = lane >> 4;   // row-in-group 0..3
  const int q = lane & 15;    // 16B-seg index
  const int c0 = w << 6;
  const float* xwp = xb + (size_t)(c0 + cr) * HW + q * 4;

  float4 s4[NP];
#pragma unroll
  for (int p = 0; p < NP; ++p) s4[p] = make_float4(0.f, 0.f, 0.f, 0.f);

#pragma unroll
  for (int h = 0; h < 2; ++h) {
    float4 xv[8];
#pragma unroll
    for (int i = 0; i < 8; ++i)   // 8 back-to-back 1KB wave-loads
      xv[i] = *(const float4*)(xwp + (size_t)(h * 32 + i * 4) * HW);
#pragma unroll
    for (int i = 0; i < 8; ++i) { // stage into swizzled LDS tile
      int c = c0 + h * 32 + i * 4 + cr;
      *(float4*)&xs[c][(q ^ (c & 7)) << 2] = xv[i];
    }
    A_BATCH(xv, h * 32)
  }

  // csub-reduce once (lane bits 4,5); cr==0 lanes write sp
#pragma unroll
  for (int p = 0; p < NP; ++p) {
    float4 v = s4[p];
    v.x += __shfl_xor(v.x, 16); v.y += __shfl_xor(v.y, 16);
    v.z += __shfl_xor(v.z, 16); v.w += __shfl_xor(v.w, 16);
    v.x += __shfl_xor(v.x, 32); v.y += __shfl_xor(v.y, 32);
    v.z += __shfl_xor(v.z, 32); v.w += __shfl_xor(v.w, 32);
    if (cr == 0) *(float4*)&sp[w][p][q * 4] = v;
  }
  __syncthreads();   // wt reads done; xs writes visible

  // ---- e = exp(score + bias) -> els (overlays wt); psum partial ----
  {
    const int ep = t >> 5, eh = t & 31;
    float a0 = bias[ep], a1 = a0;
#pragma unroll
    for (int ww = 0; ww < 4; ++ww) {
      a0 += sp[ww][ep][eh];
      a1 += sp[ww][ep][eh + 32];
    }
    float e0 = expf(a0), e1 = expf(a1);
    ELS(ep, eh) = e0;
    ELS(ep, eh + 32) = e1;
    float esum = e0 + e1;
#pragma unroll
    for (int off = 16; off; off >>= 1) esum += __shfl_xor(esum, off);
    if (eh == 0) psum[bid * NP + ep] = esum;
  }
  __syncthreads();

  // ---- Phase B: pool; thread = row c = t; x from swizzled LDS ----
  const int tk = t & 7;
  float acc[NP];
#pragma unroll
  for (int p = 0; p < NP; ++p) acc[p] = 0.f;

#pragma unroll
  for (int h = 0; h < 2; ++h) {
    float4 xv[8];
#pragma unroll
    for (int j = 0; j < 8; ++j) {
      int k = h * 8 + j;
      xv[j] = *(const float4*)&xs[t][(k ^ tk) << 2];  // logical seg k
    }
#pragma unroll
    for (int j = 0; j < 8; ++j) {
      const int k = h * 8 + j;
#pragma unroll
      for (int p = 0; p < NP; ++p) {
        float4 e4 = *(const float4*)&ELS(p, k * 4);   // uniform -> broadcast
        acc[p] = fmaf(xv[j].x, e4.x, acc[p]);
        acc[p] = fmaf(xv[j].y, e4.y, acc[p]);
        acc[p] = fmaf(xv[j].z, e4.z, acc[p]);
        acc[p] = fmaf(xv[j].w, e4.w, acc[p]);
      }
    }
  }

  // ---- coalesced partial write: partial[bid][p][c] ----
#pragma unroll
  for (int p = 0; p < NP; ++p)
    partial[((size_t)bid * NP + p) * NC + t] = acc[p];
}

// ---------------- Reduce: out[b,p,c] = ginv * sum_ch partial ----------------
__global__ __launch_bounds__(256) void k_reduce(
    const float* __restrict__ partial, const float* __restrict__ psum,
    float* __restrict__ out) {
  int bp = blockIdx.x;  // b*8 + p
  int b = bp >> 3, p = bp & 7;
  int t = threadIdx.x, lane = t & 63, w2 = t >> 6;

  __shared__ float gv;
  if (w2 == 0) {
    float v = psum[(size_t)(b * NCH + lane) * NP + p];
#pragma unroll
    for (int off = 32; off; off >>= 1) v += __shfl_xor(v, off);
    if (lane == 0) gv = 1.0f / (v * (float)HW);
  }
  __syncthreads();
  float ginv = gv;

  float acc = 0.f;
#pragma unroll 16
  for (int ch = 0; ch < NCH; ++ch)
    acc += partial[(((size_t)b * NCH + ch) * NP + p) * NC + t];
  out[((size_t)b * NP + p) * NC + t] = acc * ginv;
}

extern "C" void kernel_launch(void* const* d_in, const int* in_sizes, int n_in,
                              void* d_out, int out_size, void* d_ws, size_t ws_size,
                              hipStream_t stream) {
  const float* x = (const float*)d_in[0];
  const float* Wm = (const float*)d_in[1];
  const float* bias = (const float*)d_in[2];
  float* out = (float*)d_out;

  float* ws = (float*)d_ws;
  float* partial = ws;                                  // 2048*8*256 floats = 16 MiB
  float* psum = ws + (size_t)NB * NCH * NP * NC;        // 2048*8 floats

  k_fused<<<NB * NCH, 256, 0, stream>>>(x, Wm, bias, partial, psum);
  k_reduce<<<NB * NP, 256, 0, stream>>>(partial, psum, out);
}